// Round 5
// baseline (809.134 us; speedup 1.0000x reference)
//
#include <hip/hip_runtime.h>
#include <math.h>

typedef __bf16 bf16x8 __attribute__((ext_vector_type(8)));
typedef float f32x4 __attribute__((ext_vector_type(4)));

// ---------------- bf16 helpers ----------------
__device__ __forceinline__ unsigned short f2bf(float f) {
    unsigned u = __float_as_uint(f);
    return (unsigned short)((u + 0x7fffu + ((u >> 16) & 1u)) >> 16);
}
__device__ __forceinline__ float2 bf2(unsigned u) {
    float2 r;
    r.x = __uint_as_float(u << 16);
    r.y = __uint_as_float(u & 0xffff0000u);
    return r;
}

// ---------------- prep: x -> bf16 ----------------
__global__ __launch_bounds__(256) void convert_x(
    const float* __restrict__ x, unsigned short* __restrict__ xb, int total)
{
    int g = blockIdx.x * blockDim.x + threadIdx.x;
    if (g < total) xb[g] = f2bf(x[g]);
}

// ---------------- prep: 640-col transposed bf16 weights + folded bias ----------------
// Output-column order == final P position (kv interleave baked in):
//   p in [0,256): cc = 2*(p>>2)+(p&1), W = (p&2)?Wv:Wk, +be folded.
//   [256,384)=q (Wq,bq); [384,512)=s (Ws,bs);
//   [512,640): qWe fused cols: Wt[c][d] = sum_i Wq[d,h*C+i]*We[kk*128+h*C+i].
__global__ __launch_bounds__(256) void prep_w(
    const float* __restrict__ Wq, const float* __restrict__ bq,
    const float* __restrict__ Wk, const float* __restrict__ bk,
    const float* __restrict__ Wv, const float* __restrict__ bv,
    const float* __restrict__ be,
    const float* __restrict__ Ws, const float* __restrict__ bs,
    const float* __restrict__ We, int H,
    unsigned short* __restrict__ Wt, float* __restrict__ bias)
{
    int g = blockIdx.x * blockDim.x + threadIdx.x;
    const int C = 128 / H;
    if (g < 640) {
        int p = g;
        float b;
        if (p < 256) {
            int cc = 2 * (p >> 2) + (p & 1);
            b = ((p & 2) ? bv[cc] : bk[cc]) + be[cc];
        }
        else if (p < 384) b = bq[p - 256];
        else if (p < 512) b = bs[p - 384];
        else {
            int c2 = p - 512, h = c2 >> 4, kk = c2 & 15;
            b = 0.f;
            if (h < H) for (int i = 0; i < C; ++i) b += bq[h * C + i] * We[kk * 128 + h * C + i];
        }
        bias[p] = b;
    }
    if (g >= 640 * 128) return;
    int p = g >> 7, d = g & 127;
    float w;
    if (p < 256) {
        int cc = 2 * (p >> 2) + (p & 1);
        w = (p & 2) ? Wv[d * 128 + cc] : Wk[d * 128 + cc];
    } else if (p < 384) {
        w = Wq[d * 128 + (p - 256)];
    } else if (p < 512) {
        w = Ws[d * 128 + (p - 384)];
    } else {
        int c2 = p - 512, h = c2 >> 4, kk = c2 & 15;
        w = 0.f;
        if (h < H) for (int i = 0; i < C; ++i) w += Wq[d * 128 + h * C + i] * We[kk * 128 + h * C + i];
    }
    Wt[(size_t)p * 128 + d] = f2bf(w);
}

// ---------------- MFMA bf16 GEMM: [P | qWe] = Xb[m,128] @ Wt + bias ----------------
// Round-0 structure (2D grid). B tile (64 cols x 128 k, 16 KB) staged in
// LDS. C-frag: col=lane&15, row=(lane>>4)*4+reg [m89/m91]. Epilogue via
// LDS for coalesced stores.
__global__ __launch_bounds__(256) void gemm_bf16(
    const unsigned short* __restrict__ Xb, int M,
    const unsigned short* __restrict__ Wt, const float* __restrict__ bias,
    unsigned short* __restrict__ P, float* __restrict__ qWe)
{
    __shared__ unsigned short Bs[64][136];
    __shared__ unsigned short tile[4][16][64];
    const int wv = threadIdx.x >> 6, lane = threadIdx.x & 63;
    const int row0 = blockIdx.x * 64 + wv * 16;
    const int n0 = blockIdx.y * 64;                 // [0,640)
    const int quad = lane >> 4, l16 = lane & 15;

    {   // stage Wt column-tile into LDS: 1024 x uint4, coalesced
        const uint4* gsrc = (const uint4*)(Wt + (size_t)n0 * 128);
#pragma unroll
        for (int u = 0; u < 4; ++u) {
            int v = threadIdx.x + u * 256;
            int col = v >> 4, k8 = v & 15;
            *(uint4*)(&Bs[col][k8 * 8]) = gsrc[v];
        }
    }
    __syncthreads();

    f32x4 acc[4] = {};
    int mrow = row0 + l16; if (mrow >= M) mrow = M - 1;  // clamp loads; stores guarded
    const int kb = quad * 8;
#pragma unroll
    for (int kk = 0; kk < 4; ++kk) {
        bf16x8 a = *(const bf16x8*)(Xb + (size_t)mrow * 128 + kk * 32 + kb);
#pragma unroll
        for (int f = 0; f < 4; ++f) {
            bf16x8 b = *(const bf16x8*)(&Bs[f * 16 + l16][kk * 32 + kb]);
            acc[f] = __builtin_amdgcn_mfma_f32_16x16x32_bf16(a, b, acc[f], 0, 0, 0);
        }
    }
    if (n0 < 512) {
#pragma unroll
        for (int f = 0; f < 4; ++f) {
            float bs = bias[n0 + f * 16 + l16];
#pragma unroll
            for (int r = 0; r < 4; ++r) {
                int row = quad * 4 + r;
                int col = f * 16 + l16;
                tile[wv][row][col ^ ((row & 3) << 4)] = f2bf(acc[f][r] + bs);
            }
        }
        __syncthreads();
        int row = lane >> 2, seg = lane & 3;
        int m = row0 + row;
        if (m < M) {
            const uint4* src = (const uint4*)&tile[wv][row][(seg ^ (row & 3)) << 4];
            uint4* dst = (uint4*)(P + (size_t)m * 512 + n0 + seg * 16);
            dst[0] = src[0];
            dst[1] = src[1];
        }
    } else {
#pragma unroll
        for (int f = 0; f < 4; ++f) {
            int c = n0 + f * 16 + l16;
            float bs = bias[c];
#pragma unroll
            for (int r = 0; r < 4; ++r) {
                int m = row0 + quad * 4 + r;
                if (m < M) qWe[(size_t)m * 128 + (c - 512)] = acc[f][r] + bs;
            }
        }
    }
}

// ---------------- CSR build (int atomics only) ----------------
__global__ __launch_bounds__(256) void degree_kernel(
    const int* __restrict__ ei, int* __restrict__ deg, int E)
{
    int e = blockIdx.x * blockDim.x + threadIdx.x;
    if (e < E) atomicAdd(&deg[ei[E + e]], 1);
}

__global__ __launch_bounds__(1024) void scan_kernel(
    const int* __restrict__ deg, int* __restrict__ rowptr,
    int* __restrict__ cursor, int N)
{
    __shared__ int sums[1024];
    const int T = 1024;
    const int C = (N + T - 1) / T;
    const int t = threadIdx.x;
    const int b0 = t * C;
    int s = 0;
    for (int i = 0; i < C; ++i) { int idx = b0 + i; if (idx < N) s += deg[idx]; }
    sums[t] = s;
    __syncthreads();
    for (int ofs = 1; ofs < 1024; ofs <<= 1) {
        int v = (t >= ofs) ? sums[t - ofs] : 0;
        __syncthreads();
        sums[t] += v;
        __syncthreads();
    }
    int run = (t == 0) ? 0 : sums[t - 1];
    if (t == 0) rowptr[0] = 0;
    for (int i = 0; i < C; ++i) {
        int idx = b0 + i;
        if (idx < N) {
            int d = deg[idx];
            cursor[idx] = run;
            run += d;
            rowptr[idx + 1] = run;
        }
    }
}

__global__ __launch_bounds__(256) void scatter_kernel(
    const int* __restrict__ ei, int* __restrict__ cursor,
    int2* __restrict__ csr, int E)
{
    int e = blockIdx.x * blockDim.x + threadIdx.x;
    if (e < E) {
        int pos = atomicAdd(&cursor[ei[E + e]], 1);
        csr[pos] = make_int2(ei[e], e);   // (src, edge id)
    }
}

// ---------------- fused score + online-softmax + aggregation ----------------
// 32 lanes per node slice, TWO edges per wave instruction. Lane covers 4
// channels (uint4 = k2|v2|k2|v2); half = lane>>5 handles edge parity.
// 16-edge chunks: loads-only gather phase (8 kv + 8 ea in flight),
// then score/softmax/accumulate. Halves combined via xor-32 in the epilogue.
//
// ROUND 4/5: PERSISTENT grid-stride waves. Round-3 counters showed occupancy
// stuck at 41% (13/32 waves/CU) with 25000 tiny blocks — workgroup
// launch/drain rate capped residency, not VGPRs (64) or LDS (0). Launch
// 2048 blocks x 256 threads (8 blocks/CU x 4 waves = full 32 waves/CU);
// each wave loops node += total_waves. NO state is live across node
// iterations (r2 lesson: zero added loop-carried registers -> no spills).
__global__ __launch_bounds__(256) void fused1_node(
    const unsigned short* __restrict__ P, const float* __restrict__ qWe,
    const float* __restrict__ ea, const float* __restrict__ We1,
    const int2* __restrict__ csr, const int* __restrict__ rowptr,
    unsigned short* __restrict__ h1, int N)
{
    const int lane = threadIdx.x & 63;
    const int wid = (blockIdx.x * blockDim.x + threadIdx.x) >> 6;   // global wave id
    const int nw = (gridDim.x * blockDim.x) >> 6;                   // total waves
    const int l32 = lane & 31, half = lane >> 5;
    const int sub4 = l32 & 3;
    const int c0 = l32 * 4;
    const int hsrc = (lane & 32) | (l32 & 28);   // my half's slot-owner base for my head

    for (int node = wid; node < N; node += nw) {
        const int beg = rowptr[node];
        const int deg = rowptr[node + 1] - beg;

        uint2 su = *(const uint2*)(P + (size_t)node * 512 + 384 + c0);
        float2 ska = bf2(su.x), skb = bf2(su.y);
        if (deg == 0) {
            if (half == 0) {
                float o0 = ska.x > 0.f ? ska.x : 0.01f * ska.x;
                float o1 = ska.y > 0.f ? ska.y : 0.01f * ska.y;
                float o2 = skb.x > 0.f ? skb.x : 0.01f * skb.x;
                float o3 = skb.y > 0.f ? skb.y : 0.01f * skb.y;
                uint2 pk;
                pk.x = (unsigned)f2bf(o0) | ((unsigned)f2bf(o1) << 16);
                pk.y = (unsigned)f2bf(o2) | ((unsigned)f2bf(o3) << 16);
                *(uint2*)(h1 + (size_t)node * 128 + c0) = pk;
            }
            continue;
        }

        uint2 qu = *(const uint2*)(P + (size_t)node * 512 + 256 + c0);
        float2 qa = bf2(qu.x), qb = bf2(qu.y);
        float4 qw4 = *(const float4*)(qWe + (size_t)node * 128 + c0);

        float4 acc = make_float4(0.f, 0.f, 0.f, 0.f);
        float4 A2  = make_float4(0.f, 0.f, 0.f, 0.f);
        float m = -INFINITY, lden = 0.f;

        int2 se = make_int2(0, 0);
        if (lane < deg) se = csr[beg + lane];

        for (int blk = 0; blk < deg; blk += 64) {
            if (blk) se = (blk + lane < deg) ? csr[beg + blk + lane] : make_int2(0, 0);
            const int bcnt = min(64, deg - blk);
            for (int cb = 0; cb < bcnt; cb += 16) {
                const int lim = min(16, bcnt - cb);
                uint4 kv[8]; float4 ea4[8];
                // ---- gather phase: loads only, up to 16 in flight ----
#pragma unroll
                for (int i = 0; i < 8; ++i) {
                    if (2 * i < lim) {   // wave-uniform
                        int jj = cb + 2 * i + half;
                        int jc = min(jj, bcnt - 1);
                        int sb = __shfl(se.x, jc, 64);
                        int eb = __shfl(se.y, jc, 64);
                        kv[i]  = *(const uint4*)(P + (size_t)sb * 512 + l32 * 8);
                        ea4[i] = *(const float4*)(ea + (size_t)eb * 16 + sub4 * 4);
                    }
                }
                // ---- score phase ----
                float s0 = -INFINITY, s1 = -INFINITY;
#pragma unroll
                for (int i = 0; i < 8; ++i) {
                    if (2 * i < lim) {
                        float2 ka = bf2(kv[i].x), kb = bf2(kv[i].z);
                        float p = qa.x * ka.x + qa.y * ka.y + qb.x * kb.x + qb.y * kb.y
                                + qw4.x * ea4[i].x + qw4.y * ea4[i].y
                                + qw4.z * ea4[i].z + qw4.w * ea4[i].w;
                        p += __shfl_xor(p, 1, 64);
                        p += __shfl_xor(p, 2, 64);    // 4-lane head group
                        bool valid = (cb + 2 * i + half) < bcnt;
                        float pv = valid ? p * 0.25f : -INFINITY;   // 1/sqrt(16)
                        if (sub4 == (i & 3)) { if (i < 4) s0 = pv; else s1 = pv; }
                    }
                }
                // ---- online softmax update (per head, across halves) ----
                float cm = fmaxf(s0, s1);
                cm = fmaxf(cm, __shfl_xor(cm, 1, 64));
                cm = fmaxf(cm, __shfl_xor(cm, 2, 64));
                cm = fmaxf(cm, __shfl_xor(cm, 32, 64));
                float m_new = fmaxf(m, cm);
                float scale = __expf(m - m_new);      // first chunk: exp(-inf)=0
                float e0 = __expf(s0 - m_new);        // unassigned slots: 0
                float e1 = __expf(s1 - m_new);
                float ds = e0 + e1;
                ds += __shfl_xor(ds, 1, 64);
                ds += __shfl_xor(ds, 2, 64);
                ds += __shfl_xor(ds, 32, 64);
                lden = lden * scale + ds;
                acc.x *= scale; acc.y *= scale; acc.z *= scale; acc.w *= scale;
                A2.x  *= scale; A2.y  *= scale; A2.z  *= scale; A2.w  *= scale;
                m = m_new;
                // ---- accumulate phase (my half's edges only) ----
#pragma unroll
                for (int i = 0; i < 8; ++i) {
                    if (2 * i < lim) {
                        float w = __shfl((i < 4) ? e0 : e1, hsrc | (i & 3), 64);
                        float2 va = bf2(kv[i].y), vb = bf2(kv[i].w);
                        acc.x += w * va.x; acc.y += w * va.y;
                        acc.z += w * vb.x; acc.w += w * vb.y;
                        A2.x += w * ea4[i].x; A2.y += w * ea4[i].y;
                        A2.z += w * ea4[i].z; A2.w += w * ea4[i].w;
                    }
                }
            }
        }
        // combine halves
        acc.x += __shfl_xor(acc.x, 32, 64); acc.y += __shfl_xor(acc.y, 32, 64);
        acc.z += __shfl_xor(acc.z, 32, 64); acc.w += __shfl_xor(acc.w, 32, 64);
        A2.x  += __shfl_xor(A2.x, 32, 64);  A2.y  += __shfl_xor(A2.y, 32, 64);
        A2.z  += __shfl_xor(A2.z, 32, 64);  A2.w  += __shfl_xor(A2.w, 32, 64);

        // expand A_h through We1
        float ex0 = 0.f, ex1 = 0.f, ex2 = 0.f, ex3 = 0.f;
#pragma unroll
        for (int k = 0; k < 16; ++k) {
            float comp = (k & 3) == 0 ? A2.x : (k & 3) == 1 ? A2.y : (k & 3) == 2 ? A2.z : A2.w;
            float ak = __shfl(comp, hsrc | (k >> 2), 64);
            float4 w4 = *(const float4*)(We1 + k * 128 + c0);
            ex0 += ak * w4.x; ex1 += ak * w4.y; ex2 += ak * w4.z; ex3 += ak * w4.w;
        }
        float inv = 1.f / (lden + 1e-16f);
        float o0 = (acc.x + ex0) * inv + ska.x;
        float o1 = (acc.y + ex1) * inv + ska.y;
        float o2 = (acc.z + ex2) * inv + skb.x;
        float o3 = (acc.w + ex3) * inv + skb.y;
        o0 = o0 > 0.f ? o0 : 0.01f * o0;
        o1 = o1 > 0.f ? o1 : 0.01f * o1;
        o2 = o2 > 0.f ? o2 : 0.01f * o2;
        o3 = o3 > 0.f ? o3 : 0.01f * o3;
        if (half == 0) {
            uint2 pk;
            pk.x = (unsigned)f2bf(o0) | ((unsigned)f2bf(o1) << 16);
            pk.y = (unsigned)f2bf(o2) | ((unsigned)f2bf(o3) << 16);
            *(uint2*)(h1 + (size_t)node * 128 + c0) = pk;
        }
    }
}

// Layer 2: H=1, C=128. Half-wave (32-lane) dot per edge; lanes 0..7 of each
// half hold the chunk's scores. Same persistent grid-stride as fused1_node.
__global__ __launch_bounds__(256) void fused2_node(
    const unsigned short* __restrict__ P, const float* __restrict__ qWe,
    const float* __restrict__ ea, const float* __restrict__ We2,
    const int2* __restrict__ csr, const int* __restrict__ rowptr,
    float* __restrict__ out, int N)
{
    const int lane = threadIdx.x & 63;
    const int wid = (blockIdx.x * blockDim.x + threadIdx.x) >> 6;
    const int nw = (gridDim.x * blockDim.x) >> 6;
    const int l32 = lane & 31, half = lane >> 5;
    const int c0 = l32 * 4;
    const int k16 = lane & 15;

    for (int node = wid; node < N; node += nw) {
        const int beg = rowptr[node];
        const int deg = rowptr[node + 1] - beg;

        uint2 su = *(const uint2*)(P + (size_t)node * 512 + 384 + c0);
        float2 ska = bf2(su.x), skb = bf2(su.y);
        float* outp = out + (size_t)node * 128 + c0;
        if (deg == 0) {
            if (half == 0) *(float4*)outp = make_float4(ska.x, ska.y, skb.x, skb.y);
            continue;
        }

        uint2 qu = *(const uint2*)(P + (size_t)node * 512 + 256 + c0);
        float2 qa = bf2(qu.x), qb = bf2(qu.y);
        float qw = qWe[(size_t)node * 128 + k16];

        float4 acc = make_float4(0.f, 0.f, 0.f, 0.f);
        float accA = 0.f;
        float m = -INFINITY, lden = 0.f;

        int2 se = make_int2(0, 0);
        if (lane < deg) se = csr[beg + lane];

        for (int blk = 0; blk < deg; blk += 64) {
            if (blk) se = (blk + lane < deg) ? csr[beg + blk + lane] : make_int2(0, 0);
            const int bcnt = min(64, deg - blk);
            for (int cb = 0; cb < bcnt; cb += 16) {
                const int lim = min(16, bcnt - cb);
                uint4 kv[8]; float eav[8];
                // ---- gather phase ----
#pragma unroll
                for (int i = 0; i < 8; ++i) {
                    if (2 * i < lim) {
                        int jj = cb + 2 * i + half;
                        int jc = min(jj, bcnt - 1);
                        int sb = __shfl(se.x, jc, 64);
                        int eb = __shfl(se.y, jc, 64);
                        kv[i]  = *(const uint4*)(P + (size_t)sb * 512 + l32 * 8);
                        eav[i] = ea[(size_t)eb * 16 + k16];
                    }
                }
                // ---- score phase ----
                float my_s = -INFINITY;
#pragma unroll
                for (int i = 0; i < 8; ++i) {
                    if (2 * i < lim) {
                        float2 ka = bf2(kv[i].x), kb = bf2(kv[i].z);
                        float p = qa.x * ka.x + qa.y * ka.y + qb.x * kb.x + qb.y * kb.y
                                + 0.5f * qw * eav[i];   // 2x dup within half
                        p += __shfl_xor(p, 1, 64);
                        p += __shfl_xor(p, 2, 64);
                        p += __shfl_xor(p, 4, 64);
                        p += __shfl_xor(p, 8, 64);
                        p += __shfl_xor(p, 16, 64);     // half-wide reduction
                        bool valid = (cb + 2 * i + half) < bcnt;
                        if (l32 == i) my_s = valid ? p * 0.08838834764831845f : -INFINITY;
                    }
                }
                // ---- online softmax ----
                float cm = my_s;
#pragma unroll
                for (int mk = 1; mk < 64; mk <<= 1) cm = fmaxf(cm, __shfl_xor(cm, mk, 64));
                float m_new = fmaxf(m, cm);
                float scale = __expf(m - m_new);
                float ew = __expf(my_s - m_new);   // non-slot / invalid: 0
                float ds = ew;
#pragma unroll
                for (int mk = 1; mk < 64; mk <<= 1) ds += __shfl_xor(ds, mk, 64);
                lden = lden * scale + ds;
                acc.x *= scale; acc.y *= scale; acc.z *= scale; acc.w *= scale;
                accA *= scale;
                m = m_new;
                // ---- accumulate (my half's edges) ----
#pragma unroll
                for (int i = 0; i < 8; ++i) {
                    if (2 * i < lim) {
                        float w = __shfl(ew, (lane & 32) | i, 64);
                        float2 va = bf2(kv[i].y), vb = bf2(kv[i].w);
                        acc.x += w * va.x; acc.y += w * va.y;
                        acc.z += w * vb.x; acc.w += w * vb.y;
                        accA += w * eav[i];
                    }
                }
            }
        }
        // combine halves
        acc.x += __shfl_xor(acc.x, 32, 64); acc.y += __shfl_xor(acc.y, 32, 64);
        acc.z += __shfl_xor(acc.z, 32, 64); acc.w += __shfl_xor(acc.w, 32, 64);
        accA  += __shfl_xor(accA, 32, 64);

        float ex0 = 0.f, ex1 = 0.f, ex2 = 0.f, ex3 = 0.f;
#pragma unroll
        for (int k = 0; k < 16; ++k) {
            float ak = __shfl(accA, (lane & 48) | k, 64);
            float4 w4 = *(const float4*)(We2 + k * 128 + c0);
            ex0 += ak * w4.x; ex1 += ak * w4.y; ex2 += ak * w4.z; ex3 += ak * w4.w;
        }
        float inv = 1.f / (lden + 1e-16f);
        if (half == 0) {
            float4 o;
            o.x = (acc.x + ex0) * inv + ska.x;
            o.y = (acc.y + ex1) * inv + ska.y;
            o.z = (acc.z + ex2) * inv + skb.x;
            o.w = (acc.w + ex3) * inv + skb.y;
            *(float4*)outp = o;
        }
    }
}

// ---------------- launch ----------------
extern "C" void kernel_launch(void* const* d_in, const int* in_sizes, int n_in,
                              void* d_out, int out_size, void* d_ws, size_t ws_size,
                              hipStream_t stream)
{
    const float* x  = (const float*)d_in[0];
    const int*   ei = (const int*)d_in[1];
    const float* ea = (const float*)d_in[2];
    const float *Wq1 = (const float*)d_in[3],  *bq1 = (const float*)d_in[4];
    const float *Wk1 = (const float*)d_in[5],  *bk1 = (const float*)d_in[6];
    const float *Wv1 = (const float*)d_in[7],  *bv1 = (const float*)d_in[8];
    const float *We1 = (const float*)d_in[9],  *be1 = (const float*)d_in[10];
    const float *Ws1 = (const float*)d_in[11], *bs1 = (const float*)d_in[12];
    const float *Wq2 = (const float*)d_in[13], *bq2 = (const float*)d_in[14];
    const float *Wk2 = (const float*)d_in[15], *bk2 = (const float*)d_in[16];
    const float *Wv2 = (const float*)d_in[17], *bv2 = (const float*)d_in[18];
    const float *We2 = (const float*)d_in[19], *be2 = (const float*)d_in[20];
    const float *Ws2 = (const float*)d_in[21], *bs2 = (const float*)d_in[22];

    const int N = in_sizes[0] / 128;
    const int E = in_sizes[1] / 2;

    char* ws = (char*)d_ws;
    size_t off = 0;
    auto alloc = [&](size_t bytes) -> void* {
        void* p = ws + off;
        off = (off + bytes + 255) & ~(size_t)255;
        return p;
    };
    unsigned short* xb  = (unsigned short*)alloc((size_t)N * 128 * 2);
    unsigned short* P   = (unsigned short*)alloc((size_t)N * 512 * 2);  // bf16 [kv-interleave | q | s]
    unsigned short* h1b = (unsigned short*)alloc((size_t)N * 128 * 2);
    unsigned short* Wt1 = (unsigned short*)alloc((size_t)640 * 128 * 2);
    unsigned short* Wt2 = (unsigned short*)alloc((size_t)640 * 128 * 2);
    float* bias1 = (float*)alloc(640 * 4);
    float* bias2 = (float*)alloc(640 * 4);
    float* qWe   = (float*)alloc((size_t)N * 128 * 4);
    int*  deg    = (int*)alloc((size_t)N * 4);
    int*  rowptr = (int*)alloc((size_t)(N + 1) * 4);
    int*  cursor = (int*)alloc((size_t)N * 4);
    int2* csr    = (int2*)alloc((size_t)E * 8);

    dim3 gemm_grid1((N + 63) / 64, 10);
    dim3 gemm_grid2((N + 63) / 64, 9);   // layer-2 qWe needs only cols [512,528)
    const int tn = N * 128;
    const int prep_blocks = (640 * 128 + 255) / 256;

    // persistent fused kernels: 8 blocks/CU x 4 waves = 32 waves/CU (VGPR=64, LDS=0)
    int fused_blocks = 2048;
    const int max_fused_blocks = (N + 3) / 4;   // never launch more waves than nodes
    if (fused_blocks > max_fused_blocks) fused_blocks = max_fused_blocks;

    // ---- prep (independent of everything else) ----
    convert_x<<<(tn + 255) / 256, 256, 0, stream>>>(x, xb, tn);
    prep_w<<<prep_blocks, 256, 0, stream>>>(Wq1, bq1, Wk1, bk1, Wv1, bv1, be1, Ws1, bs1, We1, 8, Wt1, bias1);
    prep_w<<<prep_blocks, 256, 0, stream>>>(Wq2, bq2, Wk2, bk2, Wv2, bv2, be2, Ws2, bs2, We2, 1, Wt2, bias2);

    // ---- CSR build (shared by both layers) ----
    hipMemsetAsync(deg, 0, (size_t)N * 4, stream);
    degree_kernel<<<(E + 255) / 256, 256, 0, stream>>>(ei, deg, E);
    scan_kernel<<<1, 1024, 0, stream>>>(deg, rowptr, cursor, N);
    scatter_kernel<<<(E + 255) / 256, 256, 0, stream>>>(ei, cursor, csr, E);

    // ---- layer 1 (H=8, C=16, concat) ----
    gemm_bf16<<<gemm_grid1, 256, 0, stream>>>(xb, N, Wt1, bias1, P, qWe);
    fused1_node<<<fused_blocks, 256, 0, stream>>>(P, qWe, ea, We1, csr, rowptr, h1b, N);

    // ---- layer 2 (H=1, C=128, mean==identity) ----
    gemm_bf16<<<gemm_grid2, 256, 0, stream>>>(h1b, N, Wt2, bias2, P, qWe);
    fused2_node<<<fused_blocks, 256, 0, stream>>>(P, qWe, ea, We2, csr, rowptr, (float*)d_out, N);
}

// Round 6
// 653.008 us; speedup vs baseline: 1.2391x; 1.2391x over previous
//
#include <hip/hip_runtime.h>
#include <math.h>

typedef __bf16 bf16x8 __attribute__((ext_vector_type(8)));
typedef float f32x4 __attribute__((ext_vector_type(4)));

// ---------------- bf16 helpers ----------------
__device__ __forceinline__ unsigned short f2bf(float f) {
    unsigned u = __float_as_uint(f);
    return (unsigned short)((u + 0x7fffu + ((u >> 16) & 1u)) >> 16);
}
__device__ __forceinline__ float2 bf2(unsigned u) {
    float2 r;
    r.x = __uint_as_float(u << 16);
    r.y = __uint_as_float(u & 0xffff0000u);
    return r;
}

// ---------------- prep: x -> bf16 ----------------
__global__ __launch_bounds__(256) void convert_x(
    const float* __restrict__ x, unsigned short* __restrict__ xb, int total)
{
    int g = blockIdx.x * blockDim.x + threadIdx.x;
    if (g < total) xb[g] = f2bf(x[g]);
}

// ---------------- prep: 640-col transposed bf16 weights + folded bias ----------------
// Output-column order == final P position (kv interleave baked in):
//   p in [0,256): cc = 2*(p>>2)+(p&1), W = (p&2)?Wv:Wk, +be folded.
//   [256,384)=q (Wq,bq); [384,512)=s (Ws,bs);
//   [512,640): qWe fused cols: Wt[c][d] = sum_i Wq[d,h*C+i]*We[kk*128+h*C+i].
__global__ __launch_bounds__(256) void prep_w(
    const float* __restrict__ Wq, const float* __restrict__ bq,
    const float* __restrict__ Wk, const float* __restrict__ bk,
    const float* __restrict__ Wv, const float* __restrict__ bv,
    const float* __restrict__ be,
    const float* __restrict__ Ws, const float* __restrict__ bs,
    const float* __restrict__ We, int H,
    unsigned short* __restrict__ Wt, float* __restrict__ bias)
{
    int g = blockIdx.x * blockDim.x + threadIdx.x;
    const int C = 128 / H;
    if (g < 640) {
        int p = g;
        float b;
        if (p < 256) {
            int cc = 2 * (p >> 2) + (p & 1);
            b = ((p & 2) ? bv[cc] : bk[cc]) + be[cc];
        }
        else if (p < 384) b = bq[p - 256];
        else if (p < 512) b = bs[p - 384];
        else {
            int c2 = p - 512, h = c2 >> 4, kk = c2 & 15;
            b = 0.f;
            if (h < H) for (int i = 0; i < C; ++i) b += bq[h * C + i] * We[kk * 128 + h * C + i];
        }
        bias[p] = b;
    }
    if (g >= 640 * 128) return;
    int p = g >> 7, d = g & 127;
    float w;
    if (p < 256) {
        int cc = 2 * (p >> 2) + (p & 1);
        w = (p & 2) ? Wv[d * 128 + cc] : Wk[d * 128 + cc];
    } else if (p < 384) {
        w = Wq[d * 128 + (p - 256)];
    } else if (p < 512) {
        w = Ws[d * 128 + (p - 384)];
    } else {
        int c2 = p - 512, h = c2 >> 4, kk = c2 & 15;
        w = 0.f;
        if (h < H) for (int i = 0; i < C; ++i) w += Wq[d * 128 + h * C + i] * We[kk * 128 + h * C + i];
    }
    Wt[(size_t)p * 128 + d] = f2bf(w);
}

// ---------------- MFMA bf16 GEMM: [P | qWe] = Xb[m,128] @ Wt + bias ----------------
// Round-0 structure (2D grid). B tile (64 cols x 128 k, 16 KB) staged in
// LDS. C-frag: col=lane&15, row=(lane>>4)*4+reg [m89/m91]. Epilogue via
// LDS for coalesced stores.
__global__ __launch_bounds__(256) void gemm_bf16(
    const unsigned short* __restrict__ Xb, int M,
    const unsigned short* __restrict__ Wt, const float* __restrict__ bias,
    unsigned short* __restrict__ P, float* __restrict__ qWe)
{
    __shared__ unsigned short Bs[64][136];
    __shared__ unsigned short tile[4][16][64];
    const int wv = threadIdx.x >> 6, lane = threadIdx.x & 63;
    const int row0 = blockIdx.x * 64 + wv * 16;
    const int n0 = blockIdx.y * 64;                 // [0,640)
    const int quad = lane >> 4, l16 = lane & 15;

    {   // stage Wt column-tile into LDS: 1024 x uint4, coalesced
        const uint4* gsrc = (const uint4*)(Wt + (size_t)n0 * 128);
#pragma unroll
        for (int u = 0; u < 4; ++u) {
            int v = threadIdx.x + u * 256;
            int col = v >> 4, k8 = v & 15;
            *(uint4*)(&Bs[col][k8 * 8]) = gsrc[v];
        }
    }
    __syncthreads();

    f32x4 acc[4] = {};
    int mrow = row0 + l16; if (mrow >= M) mrow = M - 1;  // clamp loads; stores guarded
    const int kb = quad * 8;
#pragma unroll
    for (int kk = 0; kk < 4; ++kk) {
        bf16x8 a = *(const bf16x8*)(Xb + (size_t)mrow * 128 + kk * 32 + kb);
#pragma unroll
        for (int f = 0; f < 4; ++f) {
            bf16x8 b = *(const bf16x8*)(&Bs[f * 16 + l16][kk * 32 + kb]);
            acc[f] = __builtin_amdgcn_mfma_f32_16x16x32_bf16(a, b, acc[f], 0, 0, 0);
        }
    }
    if (n0 < 512) {
#pragma unroll
        for (int f = 0; f < 4; ++f) {
            float bs = bias[n0 + f * 16 + l16];
#pragma unroll
            for (int r = 0; r < 4; ++r) {
                int row = quad * 4 + r;
                int col = f * 16 + l16;
                tile[wv][row][col ^ ((row & 3) << 4)] = f2bf(acc[f][r] + bs);
            }
        }
        __syncthreads();
        int row = lane >> 2, seg = lane & 3;
        int m = row0 + row;
        if (m < M) {
            const uint4* src = (const uint4*)&tile[wv][row][(seg ^ (row & 3)) << 4];
            uint4* dst = (uint4*)(P + (size_t)m * 512 + n0 + seg * 16);
            dst[0] = src[0];
            dst[1] = src[1];
        }
    } else {
#pragma unroll
        for (int f = 0; f < 4; ++f) {
            int c = n0 + f * 16 + l16;
            float bs = bias[c];
#pragma unroll
            for (int r = 0; r < 4; ++r) {
                int m = row0 + quad * 4 + r;
                if (m < M) qWe[(size_t)m * 128 + (c - 512)] = acc[f][r] + bs;
            }
        }
    }
}

// ---------------- CSR build (int atomics only) ----------------
__global__ __launch_bounds__(256) void degree_kernel(
    const int* __restrict__ ei, int* __restrict__ deg, int E)
{
    int e = blockIdx.x * blockDim.x + threadIdx.x;
    if (e < E) atomicAdd(&deg[ei[E + e]], 1);
}

__global__ __launch_bounds__(1024) void scan_kernel(
    const int* __restrict__ deg, int* __restrict__ rowptr,
    int* __restrict__ cursor, int N)
{
    __shared__ int sums[1024];
    const int T = 1024;
    const int C = (N + T - 1) / T;
    const int t = threadIdx.x;
    const int b0 = t * C;
    int s = 0;
    for (int i = 0; i < C; ++i) { int idx = b0 + i; if (idx < N) s += deg[idx]; }
    sums[t] = s;
    __syncthreads();
    for (int ofs = 1; ofs < 1024; ofs <<= 1) {
        int v = (t >= ofs) ? sums[t - ofs] : 0;
        __syncthreads();
        sums[t] += v;
        __syncthreads();
    }
    int run = (t == 0) ? 0 : sums[t - 1];
    if (t == 0) rowptr[0] = 0;
    for (int i = 0; i < C; ++i) {
        int idx = b0 + i;
        if (idx < N) {
            int d = deg[idx];
            cursor[idx] = run;
            run += d;
            rowptr[idx + 1] = run;
        }
    }
}

__global__ __launch_bounds__(256) void scatter_kernel(
    const int* __restrict__ ei, int* __restrict__ cursor,
    int2* __restrict__ csr, int E)
{
    int e = blockIdx.x * blockDim.x + threadIdx.x;
    if (e < E) {
        int pos = atomicAdd(&cursor[ei[E + e]], 1);
        csr[pos] = make_int2(ei[e], e);   // (src, edge id)
    }
}

// ---------------- fused score + online-softmax + aggregation ----------------
// 32 lanes per node slice, TWO edges per wave instruction. Lane covers 4
// channels (uint4 = k2|v2|k2|v2); half = lane>>5 handles edge parity.
// 16-edge chunks: loads-only gather phase (8 kv + 8 ea in flight),
// then score/softmax/accumulate. Halves combined via xor-32 in the epilogue.
//
// ROUND 6: r0 semantics (ONE wave = ONE node, no loop-carried state) with
// r5's 256-thread block geometry. r5 proved 256-thread codegen is clean
// (VGPR 88, WRITE 200->12.5 MB = app-only); its regression came from the
// persistent loop (8192 waves, serial nodes -> 6.6 waves/CU). Here: 12500
// one-shot blocks x 4 waves; if r0's 41% occupancy was CP placement-rate
// limited, each placement now delivers 2x the waves.
__global__ __launch_bounds__(256) void fused1_node(
    const unsigned short* __restrict__ P, const float* __restrict__ qWe,
    const float* __restrict__ ea, const float* __restrict__ We1,
    const int2* __restrict__ csr, const int* __restrict__ rowptr,
    unsigned short* __restrict__ h1, int N)
{
    const int lane = threadIdx.x & 63;
    const int node = blockIdx.x * 4 + (threadIdx.x >> 6);
    if (node >= N) return;
    const int l32 = lane & 31, half = lane >> 5;
    const int sub4 = l32 & 3;
    const int c0 = l32 * 4;
    const int hsrc = (lane & 32) | (l32 & 28);   // my half's slot-owner base for my head

    const int beg = rowptr[node];
    const int deg = rowptr[node + 1] - beg;

    uint2 su = *(const uint2*)(P + (size_t)node * 512 + 384 + c0);
    float2 ska = bf2(su.x), skb = bf2(su.y);
    if (deg == 0) {
        if (half == 0) {
            float o0 = ska.x > 0.f ? ska.x : 0.01f * ska.x;
            float o1 = ska.y > 0.f ? ska.y : 0.01f * ska.y;
            float o2 = skb.x > 0.f ? skb.x : 0.01f * skb.x;
            float o3 = skb.y > 0.f ? skb.y : 0.01f * skb.y;
            uint2 pk;
            pk.x = (unsigned)f2bf(o0) | ((unsigned)f2bf(o1) << 16);
            pk.y = (unsigned)f2bf(o2) | ((unsigned)f2bf(o3) << 16);
            *(uint2*)(h1 + (size_t)node * 128 + c0) = pk;
        }
        return;
    }

    uint2 qu = *(const uint2*)(P + (size_t)node * 512 + 256 + c0);
    float2 qa = bf2(qu.x), qb = bf2(qu.y);
    float4 qw4 = *(const float4*)(qWe + (size_t)node * 128 + c0);

    float4 acc = make_float4(0.f, 0.f, 0.f, 0.f);
    float4 A2  = make_float4(0.f, 0.f, 0.f, 0.f);
    float m = -INFINITY, lden = 0.f;

    int2 se = make_int2(0, 0);
    if (lane < deg) se = csr[beg + lane];

    for (int blk = 0; blk < deg; blk += 64) {
        if (blk) se = (blk + lane < deg) ? csr[beg + blk + lane] : make_int2(0, 0);
        const int bcnt = min(64, deg - blk);
        for (int cb = 0; cb < bcnt; cb += 16) {
            const int lim = min(16, bcnt - cb);
            uint4 kv[8]; float4 ea4[8];
            // ---- gather phase: loads only, up to 16 in flight ----
#pragma unroll
            for (int i = 0; i < 8; ++i) {
                if (2 * i < lim) {   // wave-uniform
                    int jj = cb + 2 * i + half;
                    int jc = min(jj, bcnt - 1);
                    int sb = __shfl(se.x, jc, 64);
                    int eb = __shfl(se.y, jc, 64);
                    kv[i]  = *(const uint4*)(P + (size_t)sb * 512 + l32 * 8);
                    ea4[i] = *(const float4*)(ea + (size_t)eb * 16 + sub4 * 4);
                }
            }
            // ---- score phase ----
            float s0 = -INFINITY, s1 = -INFINITY;
#pragma unroll
            for (int i = 0; i < 8; ++i) {
                if (2 * i < lim) {
                    float2 ka = bf2(kv[i].x), kb = bf2(kv[i].z);
                    float p = qa.x * ka.x + qa.y * ka.y + qb.x * kb.x + qb.y * kb.y
                            + qw4.x * ea4[i].x + qw4.y * ea4[i].y
                            + qw4.z * ea4[i].z + qw4.w * ea4[i].w;
                    p += __shfl_xor(p, 1, 64);
                    p += __shfl_xor(p, 2, 64);    // 4-lane head group
                    bool valid = (cb + 2 * i + half) < bcnt;
                    float pv = valid ? p * 0.25f : -INFINITY;   // 1/sqrt(16)
                    if (sub4 == (i & 3)) { if (i < 4) s0 = pv; else s1 = pv; }
                }
            }
            // ---- online softmax update (per head, across halves) ----
            float cm = fmaxf(s0, s1);
            cm = fmaxf(cm, __shfl_xor(cm, 1, 64));
            cm = fmaxf(cm, __shfl_xor(cm, 2, 64));
            cm = fmaxf(cm, __shfl_xor(cm, 32, 64));
            float m_new = fmaxf(m, cm);
            float scale = __expf(m - m_new);      // first chunk: exp(-inf)=0
            float e0 = __expf(s0 - m_new);        // unassigned slots: 0
            float e1 = __expf(s1 - m_new);
            float ds = e0 + e1;
            ds += __shfl_xor(ds, 1, 64);
            ds += __shfl_xor(ds, 2, 64);
            ds += __shfl_xor(ds, 32, 64);
            lden = lden * scale + ds;
            acc.x *= scale; acc.y *= scale; acc.z *= scale; acc.w *= scale;
            A2.x  *= scale; A2.y  *= scale; A2.z  *= scale; A2.w  *= scale;
            m = m_new;
            // ---- accumulate phase (my half's edges only) ----
#pragma unroll
            for (int i = 0; i < 8; ++i) {
                if (2 * i < lim) {
                    float w = __shfl((i < 4) ? e0 : e1, hsrc | (i & 3), 64);
                    float2 va = bf2(kv[i].y), vb = bf2(kv[i].w);
                    acc.x += w * va.x; acc.y += w * va.y;
                    acc.z += w * vb.x; acc.w += w * vb.y;
                    A2.x += w * ea4[i].x; A2.y += w * ea4[i].y;
                    A2.z += w * ea4[i].z; A2.w += w * ea4[i].w;
                }
            }
        }
    }
    // combine halves
    acc.x += __shfl_xor(acc.x, 32, 64); acc.y += __shfl_xor(acc.y, 32, 64);
    acc.z += __shfl_xor(acc.z, 32, 64); acc.w += __shfl_xor(acc.w, 32, 64);
    A2.x  += __shfl_xor(A2.x, 32, 64);  A2.y  += __shfl_xor(A2.y, 32, 64);
    A2.z  += __shfl_xor(A2.z, 32, 64);  A2.w  += __shfl_xor(A2.w, 32, 64);

    // expand A_h through We1
    float ex0 = 0.f, ex1 = 0.f, ex2 = 0.f, ex3 = 0.f;
#pragma unroll
    for (int k = 0; k < 16; ++k) {
        float comp = (k & 3) == 0 ? A2.x : (k & 3) == 1 ? A2.y : (k & 3) == 2 ? A2.z : A2.w;
        float ak = __shfl(comp, hsrc | (k >> 2), 64);
        float4 w4 = *(const float4*)(We1 + k * 128 + c0);
        ex0 += ak * w4.x; ex1 += ak * w4.y; ex2 += ak * w4.z; ex3 += ak * w4.w;
    }
    float inv = 1.f / (lden + 1e-16f);
    float o0 = (acc.x + ex0) * inv + ska.x;
    float o1 = (acc.y + ex1) * inv + ska.y;
    float o2 = (acc.z + ex2) * inv + skb.x;
    float o3 = (acc.w + ex3) * inv + skb.y;
    o0 = o0 > 0.f ? o0 : 0.01f * o0;
    o1 = o1 > 0.f ? o1 : 0.01f * o1;
    o2 = o2 > 0.f ? o2 : 0.01f * o2;
    o3 = o3 > 0.f ? o3 : 0.01f * o3;
    if (half == 0) {
        uint2 pk;
        pk.x = (unsigned)f2bf(o0) | ((unsigned)f2bf(o1) << 16);
        pk.y = (unsigned)f2bf(o2) | ((unsigned)f2bf(o3) << 16);
        *(uint2*)(h1 + (size_t)node * 128 + c0) = pk;
    }
}

// Layer 2: H=1, C=128. Half-wave (32-lane) dot per edge; lanes 0..7 of each
// half hold the chunk's scores. Same 4-wave one-shot blocks as fused1_node.
__global__ __launch_bounds__(256) void fused2_node(
    const unsigned short* __restrict__ P, const float* __restrict__ qWe,
    const float* __restrict__ ea, const float* __restrict__ We2,
    const int2* __restrict__ csr, const int* __restrict__ rowptr,
    float* __restrict__ out, int N)
{
    const int lane = threadIdx.x & 63;
    const int node = blockIdx.x * 4 + (threadIdx.x >> 6);
    if (node >= N) return;
    const int l32 = lane & 31, half = lane >> 5;
    const int c0 = l32 * 4;
    const int k16 = lane & 15;

    const int beg = rowptr[node];
    const int deg = rowptr[node + 1] - beg;

    uint2 su = *(const uint2*)(P + (size_t)node * 512 + 384 + c0);
    float2 ska = bf2(su.x), skb = bf2(su.y);
    float* outp = out + (size_t)node * 128 + c0;
    if (deg == 0) {
        if (half == 0) *(float4*)outp = make_float4(ska.x, ska.y, skb.x, skb.y);
        return;
    }

    uint2 qu = *(const uint2*)(P + (size_t)node * 512 + 256 + c0);
    float2 qa = bf2(qu.x), qb = bf2(qu.y);
    float qw = qWe[(size_t)node * 128 + k16];

    float4 acc = make_float4(0.f, 0.f, 0.f, 0.f);
    float accA = 0.f;
    float m = -INFINITY, lden = 0.f;

    int2 se = make_int2(0, 0);
    if (lane < deg) se = csr[beg + lane];

    for (int blk = 0; blk < deg; blk += 64) {
        if (blk) se = (blk + lane < deg) ? csr[beg + blk + lane] : make_int2(0, 0);
        const int bcnt = min(64, deg - blk);
        for (int cb = 0; cb < bcnt; cb += 16) {
            const int lim = min(16, bcnt - cb);
            uint4 kv[8]; float eav[8];
            // ---- gather phase ----
#pragma unroll
            for (int i = 0; i < 8; ++i) {
                if (2 * i < lim) {
                    int jj = cb + 2 * i + half;
                    int jc = min(jj, bcnt - 1);
                    int sb = __shfl(se.x, jc, 64);
                    int eb = __shfl(se.y, jc, 64);
                    kv[i]  = *(const uint4*)(P + (size_t)sb * 512 + l32 * 8);
                    eav[i] = ea[(size_t)eb * 16 + k16];
                }
            }
            // ---- score phase ----
            float my_s = -INFINITY;
#pragma unroll
            for (int i = 0; i < 8; ++i) {
                if (2 * i < lim) {
                    float2 ka = bf2(kv[i].x), kb = bf2(kv[i].z);
                    float p = qa.x * ka.x + qa.y * ka.y + qb.x * kb.x + qb.y * kb.y
                            + 0.5f * qw * eav[i];   // 2x dup within half
                    p += __shfl_xor(p, 1, 64);
                    p += __shfl_xor(p, 2, 64);
                    p += __shfl_xor(p, 4, 64);
                    p += __shfl_xor(p, 8, 64);
                    p += __shfl_xor(p, 16, 64);     // half-wide reduction
                    bool valid = (cb + 2 * i + half) < bcnt;
                    if (l32 == i) my_s = valid ? p * 0.08838834764831845f : -INFINITY;
                }
            }
            // ---- online softmax ----
            float cm = my_s;
#pragma unroll
            for (int mk = 1; mk < 64; mk <<= 1) cm = fmaxf(cm, __shfl_xor(cm, mk, 64));
            float m_new = fmaxf(m, cm);
            float scale = __expf(m - m_new);
            float ew = __expf(my_s - m_new);   // non-slot / invalid: 0
            float ds = ew;
#pragma unroll
            for (int mk = 1; mk < 64; mk <<= 1) ds += __shfl_xor(ds, mk, 64);
            lden = lden * scale + ds;
            acc.x *= scale; acc.y *= scale; acc.z *= scale; acc.w *= scale;
            accA *= scale;
            m = m_new;
            // ---- accumulate (my half's edges) ----
#pragma unroll
            for (int i = 0; i < 8; ++i) {
                if (2 * i < lim) {
                    float w = __shfl(ew, (lane & 32) | i, 64);
                    float2 va = bf2(kv[i].y), vb = bf2(kv[i].w);
                    acc.x += w * va.x; acc.y += w * va.y;
                    acc.z += w * vb.x; acc.w += w * vb.y;
                    accA += w * eav[i];
                }
            }
        }
    }
    // combine halves
    acc.x += __shfl_xor(acc.x, 32, 64); acc.y += __shfl_xor(acc.y, 32, 64);
    acc.z += __shfl_xor(acc.z, 32, 64); acc.w += __shfl_xor(acc.w, 32, 64);
    accA  += __shfl_xor(accA, 32, 64);

    float ex0 = 0.f, ex1 = 0.f, ex2 = 0.f, ex3 = 0.f;
#pragma unroll
    for (int k = 0; k < 16; ++k) {
        float ak = __shfl(accA, (lane & 48) | k, 64);
        float4 w4 = *(const float4*)(We2 + k * 128 + c0);
        ex0 += ak * w4.x; ex1 += ak * w4.y; ex2 += ak * w4.z; ex3 += ak * w4.w;
    }
    float inv = 1.f / (lden + 1e-16f);
    if (half == 0) {
        float4 o;
        o.x = (acc.x + ex0) * inv + ska.x;
        o.y = (acc.y + ex1) * inv + ska.y;
        o.z = (acc.z + ex2) * inv + skb.x;
        o.w = (acc.w + ex3) * inv + skb.y;
        *(float4*)outp = o;
    }
}

// ---------------- launch ----------------
extern "C" void kernel_launch(void* const* d_in, const int* in_sizes, int n_in,
                              void* d_out, int out_size, void* d_ws, size_t ws_size,
                              hipStream_t stream)
{
    const float* x  = (const float*)d_in[0];
    const int*   ei = (const int*)d_in[1];
    const float* ea = (const float*)d_in[2];
    const float *Wq1 = (const float*)d_in[3],  *bq1 = (const float*)d_in[4];
    const float *Wk1 = (const float*)d_in[5],  *bk1 = (const float*)d_in[6];
    const float *Wv1 = (const float*)d_in[7],  *bv1 = (const float*)d_in[8];
    const float *We1 = (const float*)d_in[9],  *be1 = (const float*)d_in[10];
    const float *Ws1 = (const float*)d_in[11], *bs1 = (const float*)d_in[12];
    const float *Wq2 = (const float*)d_in[13], *bq2 = (const float*)d_in[14];
    const float *Wk2 = (const float*)d_in[15], *bk2 = (const float*)d_in[16];
    const float *Wv2 = (const float*)d_in[17], *bv2 = (const float*)d_in[18];
    const float *We2 = (const float*)d_in[19], *be2 = (const float*)d_in[20];
    const float *Ws2 = (const float*)d_in[21], *bs2 = (const float*)d_in[22];

    const int N = in_sizes[0] / 128;
    const int E = in_sizes[1] / 2;

    char* ws = (char*)d_ws;
    size_t off = 0;
    auto alloc = [&](size_t bytes) -> void* {
        void* p = ws + off;
        off = (off + bytes + 255) & ~(size_t)255;
        return p;
    };
    unsigned short* xb  = (unsigned short*)alloc((size_t)N * 128 * 2);
    unsigned short* P   = (unsigned short*)alloc((size_t)N * 512 * 2);  // bf16 [kv-interleave | q | s]
    unsigned short* h1b = (unsigned short*)alloc((size_t)N * 128 * 2);
    unsigned short* Wt1 = (unsigned short*)alloc((size_t)640 * 128 * 2);
    unsigned short* Wt2 = (unsigned short*)alloc((size_t)640 * 128 * 2);
    float* bias1 = (float*)alloc(640 * 4);
    float* bias2 = (float*)alloc(640 * 4);
    float* qWe   = (float*)alloc((size_t)N * 128 * 4);
    int*  deg    = (int*)alloc((size_t)N * 4);
    int*  rowptr = (int*)alloc((size_t)(N + 1) * 4);
    int*  cursor = (int*)alloc((size_t)N * 4);
    int2* csr    = (int2*)alloc((size_t)E * 8);

    dim3 gemm_grid1((N + 63) / 64, 10);
    dim3 gemm_grid2((N + 63) / 64, 9);   // layer-2 qWe needs only cols [512,528)
    const int tn = N * 128;
    const int node_blocks = (N + 3) / 4;     // 4 nodes (4 waves) per 256-thread block
    const int prep_blocks = (640 * 128 + 255) / 256;

    // ---- prep (independent of everything else) ----
    convert_x<<<(tn + 255) / 256, 256, 0, stream>>>(x, xb, tn);
    prep_w<<<prep_blocks, 256, 0, stream>>>(Wq1, bq1, Wk1, bk1, Wv1, bv1, be1, Ws1, bs1, We1, 8, Wt1, bias1);
    prep_w<<<prep_blocks, 256, 0, stream>>>(Wq2, bq2, Wk2, bk2, Wv2, bv2, be2, Ws2, bs2, We2, 1, Wt2, bias2);

    // ---- CSR build (shared by both layers) ----
    hipMemsetAsync(deg, 0, (size_t)N * 4, stream);
    degree_kernel<<<(E + 255) / 256, 256, 0, stream>>>(ei, deg, E);
    scan_kernel<<<1, 1024, 0, stream>>>(deg, rowptr, cursor, N);
    scatter_kernel<<<(E + 255) / 256, 256, 0, stream>>>(ei, cursor, csr, E);

    // ---- layer 1 (H=8, C=16, concat) ----
    gemm_bf16<<<gemm_grid1, 256, 0, stream>>>(xb, N, Wt1, bias1, P, qWe);
    fused1_node<<<node_blocks, 256, 0, stream>>>(P, qWe, ea, We1, csr, rowptr, h1b, N);

    // ---- layer 2 (H=1, C=128, mean==identity) ----
    gemm_bf16<<<gemm_grid2, 256, 0, stream>>>(h1b, N, Wt2, bias2, P, qWe);
    fused2_node<<<node_blocks, 256, 0, stream>>>(P, qWe, ea, We2, csr, rowptr, (float*)d_out, N);
}